// Round 1
// baseline (604.287 us; speedup 1.0000x reference)
//
#include <hip/hip_runtime.h>

#define IN_F 128
#define HID_F 64

// ---------------- CSR build ----------------

__global__ void k_zero2(int* __restrict__ a, int* __restrict__ b, int n) {
    int i = blockIdx.x * blockDim.x + threadIdx.x;
    if (i < n) { a[i] = 0; b[i] = 0; }
}

__global__ void k_count(const int* __restrict__ dst, int* __restrict__ count, int E) {
    int e = blockIdx.x * blockDim.x + threadIdx.x;
    if (e < E) atomicAdd(&count[dst[e]], 1);
}

// per-256-block exclusive scan of count -> rowptr (partial), block totals -> bsum,
// fused dinv = rsqrt(deg + 1 self-loop)
__global__ __launch_bounds__(256) void k_scan_a(const int* __restrict__ count,
        int* __restrict__ rowptr, int* __restrict__ bsum, float* __restrict__ dinv, int N) {
    __shared__ int s[256];
    int tid = threadIdx.x;
    int n = blockIdx.x * 256 + tid;
    int c = (n < N) ? count[n] : 0;
    s[tid] = c;
    __syncthreads();
    for (int off = 1; off < 256; off <<= 1) {
        int v = (tid >= off) ? s[tid - off] : 0;
        __syncthreads();
        s[tid] += v;
        __syncthreads();
    }
    if (n < N) {
        rowptr[n] = s[tid] - c;             // exclusive within block
        dinv[n] = rsqrtf((float)c + 1.0f);  // deg always >= 1 (self-loop)
    }
    if (tid == 255) bsum[blockIdx.x] = s[255];
}

__global__ __launch_bounds__(512) void k_scan_b(const int* __restrict__ bsum,
        int* __restrict__ boff, int nb) {
    __shared__ int s[512];
    int tid = threadIdx.x;
    int c = (tid < nb) ? bsum[tid] : 0;
    s[tid] = c;
    __syncthreads();
    for (int off = 1; off < 512; off <<= 1) {
        int v = (tid >= off) ? s[tid - off] : 0;
        __syncthreads();
        s[tid] += v;
        __syncthreads();
    }
    if (tid < nb) boff[tid] = s[tid] - c;   // exclusive block offsets
}

// add block offsets; set rowptr[N] = E   (grid/block MUST match k_scan_a blocking)
__global__ void k_scan_c(int* __restrict__ rowptr, const int* __restrict__ boff, int N, int E) {
    int n = blockIdx.x * blockDim.x + threadIdx.x;
    if (n < N) rowptr[n] += boff[blockIdx.x];
    if (n == 0) rowptr[N] = E;
}

__global__ void k_fill(const int* __restrict__ src, const int* __restrict__ dst,
                       const int* __restrict__ rowptr, int* __restrict__ cursor,
                       int* __restrict__ col, int E) {
    int e = blockIdx.x * blockDim.x + threadIdx.x;
    if (e >= E) return;
    int d = dst[e];
    int p = rowptr[d] + atomicAdd(&cursor[d], 1);
    col[p] = src[e];
}

// ---------------- GEMM: out[N,64] = A[N,K] @ W[K,64] (fp32 vector ALU) ----------------
// block 256 threads -> 64x64 tile, 4x4 micro-tile per thread, BK=32
template<int K>
__global__ __launch_bounds__(256) void k_gemm(const float* __restrict__ A,
        const float* __restrict__ W, float* __restrict__ out, int N) {
    __shared__ float As[32][68];   // transposed A tile: As[k][m], +4 pad keeps 16B align
    __shared__ float Ws[32][64];   // Ws[k][n]
    int tid = threadIdx.x;
    int tx = tid & 15, ty = tid >> 4;
    int row0 = blockIdx.x * 64;
    float acc[4][4] = {};
    for (int kt = 0; kt < K; kt += 32) {
        #pragma unroll
        for (int i = 0; i < 2; ++i) {
            int f = tid + i * 256;        // 512 float4 slots of the 64x32 A tile
            int m = f >> 3;
            int kk = (f & 7) << 2;
            int row = row0 + m;
            float4 v = {0.f, 0.f, 0.f, 0.f};
            if (row < N) v = *(const float4*)(A + (size_t)row * K + kt + kk);
            As[kk + 0][m] = v.x;
            As[kk + 1][m] = v.y;
            As[kk + 2][m] = v.z;
            As[kk + 3][m] = v.w;
        }
        #pragma unroll
        for (int i = 0; i < 2; ++i) {
            int f = tid + i * 256;        // 512 float4 slots of the 32x64 W tile
            int kk = f >> 4;
            int nn = (f & 15) << 2;
            *(float4*)&Ws[kk][nn] = *(const float4*)(W + (size_t)(kt + kk) * 64 + nn);
        }
        __syncthreads();
        #pragma unroll
        for (int kk = 0; kk < 32; ++kk) {
            float4 a4 = *(const float4*)&As[kk][ty * 4];
            float4 w4 = *(const float4*)&Ws[kk][tx * 4];
            float a[4] = {a4.x, a4.y, a4.z, a4.w};
            float w[4] = {w4.x, w4.y, w4.z, w4.w};
            #pragma unroll
            for (int i2 = 0; i2 < 4; ++i2)
                #pragma unroll
                for (int j2 = 0; j2 < 4; ++j2)
                    acc[i2][j2] += a[i2] * w[j2];
        }
        __syncthreads();
    }
    #pragma unroll
    for (int i = 0; i < 4; ++i) {
        int row = row0 + ty * 4 + i;
        if (row < N) {
            float4 v = {acc[i][0], acc[i][1], acc[i][2], acc[i][3]};
            *(float4*)(out + (size_t)row * 64 + tx * 4) = v;
        }
    }
}

// ---------------- pull aggregation: one wave per node, lane = feature ----------------
// out[n][j] = dinv[n] * ( sum_{s in CSR(n)} xw[s][j]*dinv[s] + xw[n][j]*dinv[n] ) + bias[j]
__global__ __launch_bounds__(256) void k_aggregate(const float* __restrict__ xw,
        const int* __restrict__ rowptr, const int* __restrict__ col,
        const float* __restrict__ dinv, const float* __restrict__ bias,
        float* __restrict__ out, int N, int do_relu) {
    int wave = (blockIdx.x * blockDim.x + threadIdx.x) >> 6;
    int lane = threadIdx.x & 63;
    if (wave >= N) return;
    int n = wave;
    int beg = rowptr[n], end = rowptr[n + 1];
    float dn = dinv[n];
    float acc = xw[(size_t)n * 64 + lane] * dn;   // self-loop term (x dn again below)
    for (int i = beg; i < end; ++i) {
        int s = col[i];
        acc += xw[(size_t)s * 64 + lane] * dinv[s];
    }
    float r = dn * acc + bias[lane];
    if (do_relu) r = fmaxf(r, 0.f);
    out[(size_t)n * 64 + lane] = r;
}

// ---------------- launch ----------------

extern "C" void kernel_launch(void* const* d_in, const int* in_sizes, int n_in,
                              void* d_out, int out_size, void* d_ws, size_t ws_size,
                              hipStream_t stream) {
    const float* x  = (const float*)d_in[0];
    const int*   ei = (const int*)d_in[1];
    const float* W1 = (const float*)d_in[2];
    const float* b1 = (const float*)d_in[3];
    const float* W2 = (const float*)d_in[4];
    const float* b2 = (const float*)d_in[5];
    float* out = (float*)d_out;

    const int N = in_sizes[0] / IN_F;
    const int E = in_sizes[1] / 2;
    const int* src = ei;        // edge_index[0]
    const int* dst = ei + E;    // edge_index[1]

    char* ws = (char*)d_ws;
    const size_t MB = 1u << 20;
    int*   count  = (int*)  (ws + 0 * MB);       // N ints (~400 KB)
    int*   cursor = (int*)  (ws + 1 * MB);       // N ints
    int*   rowptr = (int*)  (ws + 2 * MB);       // N+1 ints
    float* dinv   = (float*)(ws + 3 * MB);       // N floats
    int*   bsum   = (int*)  (ws + 4 * MB);       // ~391 ints
    int*   boff   = (int*)  (ws + 4 * MB + 8192);
    int*   col    = (int*)  (ws + 5 * MB);       // E ints (6.4 MB)
    float* xw     = (float*)(ws + 16 * MB);      // N*64 floats (25.6 MB), reused for layer 2
    float* h      = (float*)(ws + 48 * MB);      // N*64 floats (25.6 MB)

    const int nbN = (N + 255) / 256;             // 391 (<= 512 required for scan_b)
    const int nbE = (E + 255) / 256;

    // CSR build (shared by both layers; deg includes +1 self-loop in dinv)
    k_zero2 <<<nbN, 256, 0, stream>>>(count, cursor, N);
    k_count <<<nbE, 256, 0, stream>>>(dst, count, E);
    k_scan_a<<<nbN, 256, 0, stream>>>(count, rowptr, bsum, dinv, N);
    k_scan_b<<<1, 512, 0, stream>>>(bsum, boff, nbN);
    k_scan_c<<<nbN, 256, 0, stream>>>(rowptr, boff, N, E);
    k_fill  <<<nbE, 256, 0, stream>>>(src, dst, rowptr, cursor, col, E);

    // layer 1: xw = x @ W1 ; h = relu(aggregate(xw) + b1)
    k_gemm<IN_F> <<<(N + 63) / 64, 256, 0, stream>>>(x, W1, xw, N);
    k_aggregate  <<<(N * 64 + 255) / 256, 256, 0, stream>>>(xw, rowptr, col, dinv, b1, h, N, 1);

    // layer 2: xw = h @ W2 ; out = aggregate(xw) + b2
    k_gemm<HID_F><<<(N + 63) / 64, 256, 0, stream>>>(h, W2, xw, N);
    k_aggregate  <<<(N * 64 + 255) / 256, 256, 0, stream>>>(xw, rowptr, col, dinv, b2, out, N, 0);
}

// Round 2
// 450.495 us; speedup vs baseline: 1.3414x; 1.3414x over previous
//
#include <hip/hip_runtime.h>

#define IN_F 128
#define HID_F 64

// ---------------- CSR build ----------------

__global__ void k_count(const int* __restrict__ dst, int* __restrict__ count, int E) {
    int e = blockIdx.x * blockDim.x + threadIdx.x;
    if (e < E) atomicAdd(&count[dst[e]], 1);
}

// per-256-block exclusive scan of count -> rowptr (partial), block totals -> bsum,
// fused dinv = rsqrt(deg + 1 self-loop), fused cursor zeroing
__global__ __launch_bounds__(256) void k_scan_a(const int* __restrict__ count,
        int* __restrict__ rowptr, int* __restrict__ bsum, float* __restrict__ dinv,
        int* __restrict__ cursor, int N) {
    __shared__ int s[256];
    int tid = threadIdx.x;
    int n = blockIdx.x * 256 + tid;
    int c = (n < N) ? count[n] : 0;
    s[tid] = c;
    __syncthreads();
    for (int off = 1; off < 256; off <<= 1) {
        int v = (tid >= off) ? s[tid - off] : 0;
        __syncthreads();
        s[tid] += v;
        __syncthreads();
    }
    if (n < N) {
        rowptr[n] = s[tid] - c;             // exclusive within block
        dinv[n] = rsqrtf((float)c + 1.0f);  // deg always >= 1 (self-loop)
        cursor[n] = 0;
    }
    if (tid == 255) bsum[blockIdx.x] = s[255];
}

__global__ __launch_bounds__(512) void k_scan_b(const int* __restrict__ bsum,
        int* __restrict__ boff, int nb) {
    __shared__ int s[512];
    int tid = threadIdx.x;
    int c = (tid < nb) ? bsum[tid] : 0;
    s[tid] = c;
    __syncthreads();
    for (int off = 1; off < 512; off <<= 1) {
        int v = (tid >= off) ? s[tid - off] : 0;
        __syncthreads();
        s[tid] += v;
        __syncthreads();
    }
    if (tid < nb) boff[tid] = s[tid] - c;   // exclusive block offsets
}

// add block offsets; set rowptr[N] = E   (grid/block MUST match k_scan_a blocking)
__global__ void k_scan_c(int* __restrict__ rowptr, const int* __restrict__ boff, int N, int E) {
    int n = blockIdx.x * blockDim.x + threadIdx.x;
    if (n < N) rowptr[n] += boff[blockIdx.x];
    if (n == 0) rowptr[N] = E;
}

__global__ void k_fill(const int* __restrict__ src, const int* __restrict__ dst,
                       const int* __restrict__ rowptr, int* __restrict__ cursor,
                       int* __restrict__ col, int E) {
    int e = blockIdx.x * blockDim.x + threadIdx.x;
    if (e >= E) return;
    int d = dst[e];
    int p = rowptr[d] + atomicAdd(&cursor[d], 1);
    col[p] = src[e];
}

// ---------------- GEMM: out[N,64] = (A[N,K] @ W[K,64]) * dinv[row] ----------------
// block 256 threads -> 64x64 tile, 4x4 micro-tile per thread, BK=32
template<int K>
__global__ __launch_bounds__(256) void k_gemm(const float* __restrict__ A,
        const float* __restrict__ W, const float* __restrict__ dinv,
        float* __restrict__ out, int N) {
    __shared__ float As[32][68];   // transposed A tile: As[k][m], +4 pad keeps 16B align
    __shared__ float Ws[32][64];   // Ws[k][n]
    int tid = threadIdx.x;
    int tx = tid & 15, ty = tid >> 4;
    int row0 = blockIdx.x * 64;
    float acc[4][4] = {};
    for (int kt = 0; kt < K; kt += 32) {
        #pragma unroll
        for (int i = 0; i < 2; ++i) {
            int f = tid + i * 256;        // 512 float4 slots of the 64x32 A tile
            int m = f >> 3;
            int kk = (f & 7) << 2;
            int row = row0 + m;
            float4 v = {0.f, 0.f, 0.f, 0.f};
            if (row < N) v = *(const float4*)(A + (size_t)row * K + kt + kk);
            As[kk + 0][m] = v.x;
            As[kk + 1][m] = v.y;
            As[kk + 2][m] = v.z;
            As[kk + 3][m] = v.w;
        }
        #pragma unroll
        for (int i = 0; i < 2; ++i) {
            int f = tid + i * 256;        // 512 float4 slots of the 32x64 W tile
            int kk = f >> 4;
            int nn = (f & 15) << 2;
            *(float4*)&Ws[kk][nn] = *(const float4*)(W + (size_t)(kt + kk) * 64 + nn);
        }
        __syncthreads();
        #pragma unroll
        for (int kk = 0; kk < 32; ++kk) {
            float4 a4 = *(const float4*)&As[kk][ty * 4];
            float4 w4 = *(const float4*)&Ws[kk][tx * 4];
            float a[4] = {a4.x, a4.y, a4.z, a4.w};
            float w[4] = {w4.x, w4.y, w4.z, w4.w};
            #pragma unroll
            for (int i2 = 0; i2 < 4; ++i2)
                #pragma unroll
                for (int j2 = 0; j2 < 4; ++j2)
                    acc[i2][j2] += a[i2] * w[j2];
        }
        __syncthreads();
    }
    #pragma unroll
    for (int i = 0; i < 4; ++i) {
        int row = row0 + ty * 4 + i;
        if (row < N) {
            float dn = dinv[row];
            float4 v = {acc[i][0] * dn, acc[i][1] * dn, acc[i][2] * dn, acc[i][3] * dn};
            *(float4*)(out + (size_t)row * 64 + tx * 4) = v;
        }
    }
}

// ---------------- pull aggregation: one wave per node, lane = feature ----------------
// xws already has dinv[src] folded in:  out[n][j] = dinv[n]*(sum_col xws[s][j] + xws[n][j]) + b[j]
__global__ __launch_bounds__(256) void k_aggregate(const float* __restrict__ xws,
        const int* __restrict__ rowptr, const int* __restrict__ col,
        const float* __restrict__ dinv, const float* __restrict__ bias,
        float* __restrict__ out, int N, int do_relu) {
    int n = (blockIdx.x * blockDim.x + threadIdx.x) >> 6;
    unsigned lane = threadIdx.x & 63;
    if (n >= N) return;
    int beg = rowptr[n], end = rowptr[n + 1];
    float dn = dinv[n];
    // 4 independent accumulators; unroll-by-8 batches 8 col loads (contiguous ->
    // dwordx4 pairs) then 8 independent 256B gathers in flight per wave.
    float a0 = xws[(unsigned)n * 64u + lane];   // self-loop term (xws[n] = xw[n]*dn)
    float a1 = 0.f, a2 = 0.f, a3 = 0.f;
    int i = beg;
    for (; i + 8 <= end; i += 8) {
        int s0 = col[i + 0], s1 = col[i + 1], s2 = col[i + 2], s3 = col[i + 3];
        int s4 = col[i + 4], s5 = col[i + 5], s6 = col[i + 6], s7 = col[i + 7];
        float v0 = xws[(unsigned)s0 * 64u + lane];
        float v1 = xws[(unsigned)s1 * 64u + lane];
        float v2 = xws[(unsigned)s2 * 64u + lane];
        float v3 = xws[(unsigned)s3 * 64u + lane];
        float v4 = xws[(unsigned)s4 * 64u + lane];
        float v5 = xws[(unsigned)s5 * 64u + lane];
        float v6 = xws[(unsigned)s6 * 64u + lane];
        float v7 = xws[(unsigned)s7 * 64u + lane];
        a0 += v0 + v4;
        a1 += v1 + v5;
        a2 += v2 + v6;
        a3 += v3 + v7;
    }
    if (i + 4 <= end) {
        int s0 = col[i + 0], s1 = col[i + 1], s2 = col[i + 2], s3 = col[i + 3];
        a0 += xws[(unsigned)s0 * 64u + lane];
        a1 += xws[(unsigned)s1 * 64u + lane];
        a2 += xws[(unsigned)s2 * 64u + lane];
        a3 += xws[(unsigned)s3 * 64u + lane];
        i += 4;
    }
    for (; i < end; ++i)
        a0 += xws[(unsigned)col[i] * 64u + lane];
    float acc = (a0 + a1) + (a2 + a3);
    float r = dn * acc + bias[lane];
    if (do_relu) r = fmaxf(r, 0.f);
    out[(unsigned)n * 64u + lane] = r;
}

// ---------------- launch ----------------

extern "C" void kernel_launch(void* const* d_in, const int* in_sizes, int n_in,
                              void* d_out, int out_size, void* d_ws, size_t ws_size,
                              hipStream_t stream) {
    const float* x  = (const float*)d_in[0];
    const int*   ei = (const int*)d_in[1];
    const float* W1 = (const float*)d_in[2];
    const float* b1 = (const float*)d_in[3];
    const float* W2 = (const float*)d_in[4];
    const float* b2 = (const float*)d_in[5];
    float* out = (float*)d_out;

    const int N = in_sizes[0] / IN_F;
    const int E = in_sizes[1] / 2;
    const int* src = ei;        // edge_index[0]
    const int* dst = ei + E;    // edge_index[1]

    char* ws = (char*)d_ws;
    const size_t MB = 1u << 20;
    int*   count  = (int*)  (ws + 0 * MB);       // N ints (~400 KB)
    int*   cursor = (int*)  (ws + 1 * MB);       // N ints
    int*   rowptr = (int*)  (ws + 2 * MB);       // N+1 ints
    float* dinv   = (float*)(ws + 3 * MB);       // N floats
    int*   bsum   = (int*)  (ws + 4 * MB);       // ~391 ints
    int*   boff   = (int*)  (ws + 4 * MB + 8192);
    int*   col    = (int*)  (ws + 5 * MB);       // E ints (6.4 MB)
    float* xws    = (float*)(ws + 16 * MB);      // N*64 floats (25.6 MB), reused for layer 2
    float* h      = (float*)(ws + 48 * MB);      // N*64 floats (25.6 MB)

    const int nbN = (N + 255) / 256;             // 391 (<= 512 required for scan_b)
    const int nbE = (E + 255) / 256;

    // CSR build (shared by both layers; deg includes +1 self-loop in dinv)
    hipMemsetAsync(count, 0, (size_t)N * sizeof(int), stream);
    k_count <<<nbE, 256, 0, stream>>>(dst, count, E);
    k_scan_a<<<nbN, 256, 0, stream>>>(count, rowptr, bsum, dinv, cursor, N);
    k_scan_b<<<1, 512, 0, stream>>>(bsum, boff, nbN);
    k_scan_c<<<nbN, 256, 0, stream>>>(rowptr, boff, N, E);
    k_fill  <<<nbE, 256, 0, stream>>>(src, dst, rowptr, cursor, col, E);

    // layer 1: xws = (x @ W1) * dinv ; h = relu(dinv*(sum + self) + b1)
    k_gemm<IN_F> <<<(N + 63) / 64, 256, 0, stream>>>(x, W1, dinv, xws, N);
    k_aggregate  <<<(N * 64 + 255) / 256, 256, 0, stream>>>(xws, rowptr, col, dinv, b1, h, N, 1);

    // layer 2: xws = (h @ W2) * dinv ; out = dinv*(sum + self) + b2
    k_gemm<HID_F><<<(N + 63) / 64, 256, 0, stream>>>(h, W2, dinv, xws, N);
    k_aggregate  <<<(N * 64 + 255) / 256, 256, 0, stream>>>(xws, rowptr, col, dinv, b2, out, N, 0);
}

// Round 3
// 324.452 us; speedup vs baseline: 1.8625x; 1.3885x over previous
//
#include <hip/hip_runtime.h>

#define IN_F 128
#define HID_F 64
#define BKT_SHIFT 9            // 512 nodes per bucket
#define BKT_SIZE 512
#define CHUNK 4096             // edges per block in binning kernels

// ---------------- CSR build via 2-level bucket sort by dst ----------------
// pack: (dst & 511) << 23 | src   (needs src < 2^23, nodes/bucket <= 512)

__global__ __launch_bounds__(256) void k_bcount(const int* __restrict__ dst,
        int* __restrict__ gcount, int E) {
    __shared__ int hist[256];
    int tid = threadIdx.x;
    hist[tid] = 0;
    __syncthreads();
    int e0 = blockIdx.x * CHUNK, e1 = min(e0 + CHUNK, E);
    for (int e = e0 + tid; e < e1; e += 256)
        atomicAdd(&hist[dst[e] >> BKT_SHIFT], 1);
    __syncthreads();
    if (hist[tid]) atomicAdd(&gcount[tid], hist[tid]);
}

// single block: exclusive scan of 256 bucket counts -> bbase, gcursor; rowptr[N]=E
__global__ __launch_bounds__(256) void k_bscan(const int* __restrict__ gcount,
        int* __restrict__ bbase, int* __restrict__ gcursor,
        int* __restrict__ rowptr, int N, int E) {
    __shared__ int s[256];
    int tid = threadIdx.x;
    int c = gcount[tid];
    s[tid] = c;
    __syncthreads();
    for (int off = 1; off < 256; off <<= 1) {
        int v = (tid >= off) ? s[tid - off] : 0;
        __syncthreads();
        s[tid] += v;
        __syncthreads();
    }
    int excl = s[tid] - c;
    bbase[tid] = excl;
    gcursor[tid] = excl;
    if (tid == 255) bbase[256] = s[255];   // == E
    if (tid == 0) rowptr[N] = E;
}

__global__ __launch_bounds__(256) void k_bin(const int* __restrict__ src,
        const int* __restrict__ dst, int* __restrict__ gcursor,
        unsigned* __restrict__ gbin, int E) {
    __shared__ int hist[256];
    __shared__ int cur[256];
    int tid = threadIdx.x;
    hist[tid] = 0;
    __syncthreads();
    int e0 = blockIdx.x * CHUNK, e1 = min(e0 + CHUNK, E);
    for (int e = e0 + tid; e < e1; e += 256)
        atomicAdd(&hist[dst[e] >> BKT_SHIFT], 1);
    __syncthreads();
    if (hist[tid]) cur[tid] = atomicAdd(&gcursor[tid], hist[tid]);
    __syncthreads();
    for (int e = e0 + tid; e < e1; e += 256) {
        int d = dst[e];
        int b = d >> BKT_SHIFT;
        int p = atomicAdd(&cur[b], 1);
        gbin[p] = ((unsigned)(d & (BKT_SIZE - 1)) << 23) | (unsigned)src[e];
    }
}

// one block per bucket: per-node count (LDS), LDS scan of 512, write rowptr/dinv
// coalesced, then scatter col within the bucket's hot window via LDS cursors.
__global__ __launch_bounds__(256) void k_fill2(const unsigned* __restrict__ gbin,
        const int* __restrict__ bbase, int* __restrict__ rowptr,
        float* __restrict__ dinv, int* __restrict__ col, int N) {
    __shared__ int cnt[BKT_SIZE];
    __shared__ int pos[BKT_SIZE];
    __shared__ int s[256];
    int tid = threadIdx.x;
    int b = blockIdx.x;
    int e0 = bbase[b], e1 = bbase[b + 1];
    cnt[tid] = 0; cnt[tid + 256] = 0;
    __syncthreads();
    for (int e = e0 + tid; e < e1; e += 256)
        atomicAdd(&cnt[gbin[e] >> 23], 1);
    __syncthreads();
    int c0 = cnt[2 * tid], c1 = cnt[2 * tid + 1];
    int p2 = c0 + c1;
    s[tid] = p2;
    __syncthreads();
    for (int off = 1; off < 256; off <<= 1) {
        int v = (tid >= off) ? s[tid - off] : 0;
        __syncthreads();
        s[tid] += v;
        __syncthreads();
    }
    int excl = s[tid] - p2;
    pos[2 * tid] = excl;
    pos[2 * tid + 1] = excl + c0;
    __syncthreads();
    int n0 = b << BKT_SHIFT;
    #pragma unroll
    for (int i = tid; i < BKT_SIZE; i += 256) {
        int n = n0 + i;
        if (n < N) {
            rowptr[n] = e0 + pos[i];
            dinv[n] = rsqrtf((float)cnt[i] + 1.0f);   // +1 self-loop
        }
    }
    __syncthreads();
    for (int e = e0 + tid; e < e1; e += 256) {
        unsigned v = gbin[e];
        int p = atomicAdd(&pos[v >> 23], 1);
        col[e0 + p] = (int)(v & 0x7FFFFFu);
    }
}

// ---------------- GEMM: out[N,64] = (A[N,K] @ W[K,64]) * dinv[row] ----------------
template<int K>
__global__ __launch_bounds__(256) void k_gemm(const float* __restrict__ A,
        const float* __restrict__ W, const float* __restrict__ dinv,
        float* __restrict__ out, int N) {
    __shared__ float As[32][68];
    __shared__ float Ws[32][64];
    int tid = threadIdx.x;
    int tx = tid & 15, ty = tid >> 4;
    int row0 = blockIdx.x * 64;
    float acc[4][4] = {};
    for (int kt = 0; kt < K; kt += 32) {
        #pragma unroll
        for (int i = 0; i < 2; ++i) {
            int f = tid + i * 256;
            int m = f >> 3;
            int kk = (f & 7) << 2;
            int row = row0 + m;
            float4 v = {0.f, 0.f, 0.f, 0.f};
            if (row < N) v = *(const float4*)(A + (size_t)row * K + kt + kk);
            As[kk + 0][m] = v.x;
            As[kk + 1][m] = v.y;
            As[kk + 2][m] = v.z;
            As[kk + 3][m] = v.w;
        }
        #pragma unroll
        for (int i = 0; i < 2; ++i) {
            int f = tid + i * 256;
            int kk = f >> 4;
            int nn = (f & 15) << 2;
            *(float4*)&Ws[kk][nn] = *(const float4*)(W + (size_t)(kt + kk) * 64 + nn);
        }
        __syncthreads();
        #pragma unroll
        for (int kk = 0; kk < 32; ++kk) {
            float4 a4 = *(const float4*)&As[kk][ty * 4];
            float4 w4 = *(const float4*)&Ws[kk][tx * 4];
            float a[4] = {a4.x, a4.y, a4.z, a4.w};
            float w[4] = {w4.x, w4.y, w4.z, w4.w};
            #pragma unroll
            for (int i2 = 0; i2 < 4; ++i2)
                #pragma unroll
                for (int j2 = 0; j2 < 4; ++j2)
                    acc[i2][j2] += a[i2] * w[j2];
        }
        __syncthreads();
    }
    #pragma unroll
    for (int i = 0; i < 4; ++i) {
        int row = row0 + ty * 4 + i;
        if (row < N) {
            float dn = dinv[row];
            float4 v = {acc[i][0] * dn, acc[i][1] * dn, acc[i][2] * dn, acc[i][3] * dn};
            *(float4*)(out + (size_t)row * 64 + tx * 4) = v;
        }
    }
}

// ---------------- pull aggregation: one wave per node, lane = feature ----------------
__global__ __launch_bounds__(256) void k_aggregate(const float* __restrict__ xws,
        const int* __restrict__ rowptr, const int* __restrict__ col,
        const float* __restrict__ dinv, const float* __restrict__ bias,
        float* __restrict__ out, int N, int do_relu) {
    int n = (blockIdx.x * blockDim.x + threadIdx.x) >> 6;
    unsigned lane = threadIdx.x & 63;
    if (n >= N) return;
    int beg = rowptr[n], end = rowptr[n + 1];
    float dn = dinv[n];
    float a0 = xws[(unsigned)n * 64u + lane];   // self-loop (xws already * dinv)
    float a1 = 0.f, a2 = 0.f, a3 = 0.f;
    int i = beg;
    for (; i + 8 <= end; i += 8) {
        int s0 = col[i + 0], s1 = col[i + 1], s2 = col[i + 2], s3 = col[i + 3];
        int s4 = col[i + 4], s5 = col[i + 5], s6 = col[i + 6], s7 = col[i + 7];
        float v0 = xws[(unsigned)s0 * 64u + lane];
        float v1 = xws[(unsigned)s1 * 64u + lane];
        float v2 = xws[(unsigned)s2 * 64u + lane];
        float v3 = xws[(unsigned)s3 * 64u + lane];
        float v4 = xws[(unsigned)s4 * 64u + lane];
        float v5 = xws[(unsigned)s5 * 64u + lane];
        float v6 = xws[(unsigned)s6 * 64u + lane];
        float v7 = xws[(unsigned)s7 * 64u + lane];
        a0 += v0 + v4;
        a1 += v1 + v5;
        a2 += v2 + v6;
        a3 += v3 + v7;
    }
    if (i + 4 <= end) {
        int s0 = col[i + 0], s1 = col[i + 1], s2 = col[i + 2], s3 = col[i + 3];
        a0 += xws[(unsigned)s0 * 64u + lane];
        a1 += xws[(unsigned)s1 * 64u + lane];
        a2 += xws[(unsigned)s2 * 64u + lane];
        a3 += xws[(unsigned)s3 * 64u + lane];
        i += 4;
    }
    for (; i < end; ++i)
        a0 += xws[(unsigned)col[i] * 64u + lane];
    float acc = (a0 + a1) + (a2 + a3);
    float r = dn * acc + bias[lane];
    if (do_relu) r = fmaxf(r, 0.f);
    out[(unsigned)n * 64u + lane] = r;
}

// ---------------- launch ----------------

extern "C" void kernel_launch(void* const* d_in, const int* in_sizes, int n_in,
                              void* d_out, int out_size, void* d_ws, size_t ws_size,
                              hipStream_t stream) {
    const float* x  = (const float*)d_in[0];
    const int*   ei = (const int*)d_in[1];
    const float* W1 = (const float*)d_in[2];
    const float* b1 = (const float*)d_in[3];
    const float* W2 = (const float*)d_in[4];
    const float* b2 = (const float*)d_in[5];
    float* out = (float*)d_out;

    const int N = in_sizes[0] / IN_F;
    const int E = in_sizes[1] / 2;
    const int* src = ei;        // edge_index[0]
    const int* dst = ei + E;    // edge_index[1]

    char* ws = (char*)d_ws;
    const size_t MB = 1u << 20;
    int*      gcount  = (int*)     (ws + 0 * MB);            // 256 ints
    int*      bbase   = (int*)     (ws + 0 * MB + 4096);     // 257 ints
    int*      gcursor = (int*)     (ws + 0 * MB + 8192);     // 256 ints
    int*      rowptr  = (int*)     (ws + 1 * MB);            // N+1 ints
    float*    dinv    = (float*)   (ws + 2 * MB);            // N floats
    unsigned* gbin    = (unsigned*)(ws + 3 * MB);            // E uints (6.4 MB)
    int*      col     = (int*)     (ws + 10 * MB);           // E ints  (6.4 MB)
    float*    xws     = (float*)   (ws + 20 * MB);           // N*64 floats (25.6 MB)
    float*    h       = (float*)   (ws + 48 * MB);           // N*64 floats (25.6 MB)

    const int nbE = (E + CHUNK - 1) / CHUNK;                 // 391
    const int nbB = (N + BKT_SIZE - 1) / BKT_SIZE;           // 196 buckets (<= 256)

    hipMemsetAsync(gcount, 0, 256 * sizeof(int), stream);
    k_bcount<<<nbE, 256, 0, stream>>>(dst, gcount, E);
    k_bscan <<<1, 256, 0, stream>>>(gcount, bbase, gcursor, rowptr, N, E);
    k_bin   <<<nbE, 256, 0, stream>>>(src, dst, gcursor, gbin, E);
    k_fill2 <<<nbB, 256, 0, stream>>>(gbin, bbase, rowptr, dinv, col, N);

    // layer 1: xws = (x @ W1) * dinv ; h = relu(dinv*(sum + self) + b1)
    k_gemm<IN_F> <<<(N + 63) / 64, 256, 0, stream>>>(x, W1, dinv, xws, N);
    k_aggregate  <<<(N * 64 + 255) / 256, 256, 0, stream>>>(xws, rowptr, col, dinv, b1, h, N, 1);

    // layer 2: xws = (h @ W2) * dinv ; out = dinv*(sum + self) + b2
    k_gemm<HID_F><<<(N + 63) / 64, 256, 0, stream>>>(h, W2, dinv, xws, N);
    k_aggregate  <<<(N * 64 + 255) / 256, 256, 0, stream>>>(xws, rowptr, col, dinv, b2, out, N, 0);
}

// Round 4
// 298.299 us; speedup vs baseline: 2.0258x; 1.0877x over previous
//
#include <hip/hip_runtime.h>

#define IN_F 128
#define HID_F 64
#define BKT_SHIFT 9            // 512 nodes per bucket
#define BKT_SIZE 512
#define CHUNK 4096             // edges per block in binning kernels

typedef unsigned short ushort_t;

__device__ inline ushort_t f2bf(float f) {     // RNE fp32 -> bf16 bits
    unsigned u = __float_as_uint(f);
    u += 0x7FFFu + ((u >> 16) & 1u);
    return (ushort_t)(u >> 16);
}
__device__ inline float bf2f(ushort_t u) {
    return __uint_as_float((unsigned)u << 16);
}

// ---------------- CSR build via 2-level bucket sort by dst ----------------
// pack: (dst & 511) << 23 | src   (needs src < 2^23, nodes/bucket <= 512)

__global__ __launch_bounds__(256) void k_bcount(const int* __restrict__ dst,
        int* __restrict__ gcount, int E) {
    __shared__ int hist[256];
    int tid = threadIdx.x;
    hist[tid] = 0;
    __syncthreads();
    int e0 = blockIdx.x * CHUNK, e1 = min(e0 + CHUNK, E);
    for (int e = e0 + tid; e < e1; e += 256)
        atomicAdd(&hist[dst[e] >> BKT_SHIFT], 1);
    __syncthreads();
    if (hist[tid]) atomicAdd(&gcount[tid], hist[tid]);
}

// single block: exclusive scan of 256 bucket counts -> bbase, gcursor; rowptr[N]=E
__global__ __launch_bounds__(256) void k_bscan(const int* __restrict__ gcount,
        int* __restrict__ bbase, int* __restrict__ gcursor,
        int* __restrict__ rowptr, int N, int E) {
    __shared__ int s[256];
    int tid = threadIdx.x;
    int c = gcount[tid];
    s[tid] = c;
    __syncthreads();
    for (int off = 1; off < 256; off <<= 1) {
        int v = (tid >= off) ? s[tid - off] : 0;
        __syncthreads();
        s[tid] += v;
        __syncthreads();
    }
    int excl = s[tid] - c;
    bbase[tid] = excl;
    gcursor[tid] = excl;
    if (tid == 255) bbase[256] = s[255];   // == E
    if (tid == 0) rowptr[N] = E;
}

__global__ __launch_bounds__(256) void k_bin(const int* __restrict__ src,
        const int* __restrict__ dst, int* __restrict__ gcursor,
        unsigned* __restrict__ gbin, int E) {
    __shared__ int hist[256];
    __shared__ int cur[256];
    int tid = threadIdx.x;
    hist[tid] = 0;
    __syncthreads();
    int e0 = blockIdx.x * CHUNK, e1 = min(e0 + CHUNK, E);
    for (int e = e0 + tid; e < e1; e += 256)
        atomicAdd(&hist[dst[e] >> BKT_SHIFT], 1);
    __syncthreads();
    if (hist[tid]) cur[tid] = atomicAdd(&gcursor[tid], hist[tid]);
    __syncthreads();
    for (int e = e0 + tid; e < e1; e += 256) {
        int d = dst[e];
        int b = d >> BKT_SHIFT;
        int p = atomicAdd(&cur[b], 1);
        gbin[p] = ((unsigned)(d & (BKT_SIZE - 1)) << 23) | (unsigned)src[e];
    }
}

// one block per bucket: per-node count (LDS), LDS scan of 512, write rowptr/dinv
// coalesced, then scatter col within the bucket's hot window via LDS cursors.
__global__ __launch_bounds__(256) void k_fill2(const unsigned* __restrict__ gbin,
        const int* __restrict__ bbase, int* __restrict__ rowptr,
        float* __restrict__ dinv, int* __restrict__ col, int N) {
    __shared__ int cnt[BKT_SIZE];
    __shared__ int pos[BKT_SIZE];
    __shared__ int s[256];
    int tid = threadIdx.x;
    int b = blockIdx.x;
    int e0 = bbase[b], e1 = bbase[b + 1];
    cnt[tid] = 0; cnt[tid + 256] = 0;
    __syncthreads();
    for (int e = e0 + tid; e < e1; e += 256)
        atomicAdd(&cnt[gbin[e] >> 23], 1);
    __syncthreads();
    int c0 = cnt[2 * tid], c1 = cnt[2 * tid + 1];
    int p2 = c0 + c1;
    s[tid] = p2;
    __syncthreads();
    for (int off = 1; off < 256; off <<= 1) {
        int v = (tid >= off) ? s[tid - off] : 0;
        __syncthreads();
        s[tid] += v;
        __syncthreads();
    }
    int excl = s[tid] - p2;
    pos[2 * tid] = excl;
    pos[2 * tid + 1] = excl + c0;
    __syncthreads();
    int n0 = b << BKT_SHIFT;
    #pragma unroll
    for (int i = tid; i < BKT_SIZE; i += 256) {
        int n = n0 + i;
        if (n < N) {
            rowptr[n] = e0 + pos[i];
            dinv[n] = rsqrtf((float)cnt[i] + 1.0f);   // +1 self-loop
        }
    }
    __syncthreads();
    for (int e = e0 + tid; e < e1; e += 256) {
        unsigned v = gbin[e];
        int p = atomicAdd(&pos[v >> 23], 1);
        col[e0 + p] = (int)(v & 0x7FFFFFu);
    }
}

// ---------------- GEMM: out[N,64] = bf16((A[N,K] @ W[K,64]) * dinv[row]) ----------------
// block 256 threads -> 64x64 tile, 4x4 micro-tile per thread, BK=32
template<int K>
__global__ __launch_bounds__(256) void k_gemm(const float* __restrict__ A,
        const float* __restrict__ W, const float* __restrict__ dinv,
        ushort_t* __restrict__ out, int N) {
    __shared__ float As[32][68];
    __shared__ float Ws[32][64];
    int tid = threadIdx.x;
    int tx = tid & 15, ty = tid >> 4;
    int row0 = blockIdx.x * 64;
    float acc[4][4] = {};
    for (int kt = 0; kt < K; kt += 32) {
        #pragma unroll
        for (int i = 0; i < 2; ++i) {
            int f = tid + i * 256;
            int m = f >> 3;
            int kk = (f & 7) << 2;
            int row = row0 + m;
            float4 v = {0.f, 0.f, 0.f, 0.f};
            if (row < N) v = *(const float4*)(A + (size_t)row * K + kt + kk);
            As[kk + 0][m] = v.x;
            As[kk + 1][m] = v.y;
            As[kk + 2][m] = v.z;
            As[kk + 3][m] = v.w;
        }
        #pragma unroll
        for (int i = 0; i < 2; ++i) {
            int f = tid + i * 256;
            int kk = f >> 4;
            int nn = (f & 15) << 2;
            *(float4*)&Ws[kk][nn] = *(const float4*)(W + (size_t)(kt + kk) * 64 + nn);
        }
        __syncthreads();
        #pragma unroll
        for (int kk = 0; kk < 32; ++kk) {
            float4 a4 = *(const float4*)&As[kk][ty * 4];
            float4 w4 = *(const float4*)&Ws[kk][tx * 4];
            float a[4] = {a4.x, a4.y, a4.z, a4.w};
            float w[4] = {w4.x, w4.y, w4.z, w4.w};
            #pragma unroll
            for (int i2 = 0; i2 < 4; ++i2)
                #pragma unroll
                for (int j2 = 0; j2 < 4; ++j2)
                    acc[i2][j2] += a[i2] * w[j2];
        }
        __syncthreads();
    }
    #pragma unroll
    for (int i = 0; i < 4; ++i) {
        int row = row0 + ty * 4 + i;
        if (row < N) {
            float dn = dinv[row];
            ushort4 v;
            v.x = f2bf(acc[i][0] * dn);
            v.y = f2bf(acc[i][1] * dn);
            v.z = f2bf(acc[i][2] * dn);
            v.w = f2bf(acc[i][3] * dn);
            *(ushort4*)(out + (size_t)row * 64 + tx * 4) = v;
        }
    }
}

// ---------------- pull aggregation: one wave per node, lane = feature ----------------
// xws is bf16 with dinv[src] folded in; accumulate fp32, write fp32.
__global__ __launch_bounds__(256) void k_aggregate(const ushort_t* __restrict__ xws,
        const int* __restrict__ rowptr, const int* __restrict__ col,
        const float* __restrict__ dinv, const float* __restrict__ bias,
        float* __restrict__ out, int N, int do_relu) {
    int n = (blockIdx.x * blockDim.x + threadIdx.x) >> 6;
    unsigned lane = threadIdx.x & 63;
    if (n >= N) return;
    int beg = rowptr[n], end = rowptr[n + 1];
    float dn = dinv[n];
    float a0 = bf2f(xws[(unsigned)n * 64u + lane]);   // self-loop term
    float a1 = 0.f, a2 = 0.f, a3 = 0.f;
    float a4 = 0.f, a5 = 0.f, a6 = 0.f, a7 = 0.f;
    int i = beg;
    for (; i + 16 <= end; i += 16) {
        int s[16];
        #pragma unroll
        for (int j = 0; j < 16; ++j) s[j] = col[i + j];
        float v[16];
        #pragma unroll
        for (int j = 0; j < 16; ++j) v[j] = bf2f(xws[(unsigned)s[j] * 64u + lane]);
        a0 += v[0] + v[8];
        a1 += v[1] + v[9];
        a2 += v[2] + v[10];
        a3 += v[3] + v[11];
        a4 += v[4] + v[12];
        a5 += v[5] + v[13];
        a6 += v[6] + v[14];
        a7 += v[7] + v[15];
    }
    if (i + 8 <= end) {
        int s[8];
        #pragma unroll
        for (int j = 0; j < 8; ++j) s[j] = col[i + j];
        #pragma unroll
        for (int j = 0; j < 8; ++j) {
            float v = bf2f(xws[(unsigned)s[j] * 64u + lane]);
            if (j == 0) a0 += v; else if (j == 1) a1 += v;
            else if (j == 2) a2 += v; else if (j == 3) a3 += v;
            else if (j == 4) a4 += v; else if (j == 5) a5 += v;
            else if (j == 6) a6 += v; else a7 += v;
        }
        i += 8;
    }
    if (i + 4 <= end) {
        int s0 = col[i + 0], s1 = col[i + 1], s2 = col[i + 2], s3 = col[i + 3];
        a0 += bf2f(xws[(unsigned)s0 * 64u + lane]);
        a1 += bf2f(xws[(unsigned)s1 * 64u + lane]);
        a2 += bf2f(xws[(unsigned)s2 * 64u + lane]);
        a3 += bf2f(xws[(unsigned)s3 * 64u + lane]);
        i += 4;
    }
    for (; i < end; ++i)
        a0 += bf2f(xws[(unsigned)col[i] * 64u + lane]);
    float acc = ((a0 + a1) + (a2 + a3)) + ((a4 + a5) + (a6 + a7));
    float r = dn * acc + bias[lane];
    if (do_relu) r = fmaxf(r, 0.f);
    out[(unsigned)n * 64u + lane] = r;
}

// ---------------- launch ----------------

extern "C" void kernel_launch(void* const* d_in, const int* in_sizes, int n_in,
                              void* d_out, int out_size, void* d_ws, size_t ws_size,
                              hipStream_t stream) {
    const float* x  = (const float*)d_in[0];
    const int*   ei = (const int*)d_in[1];
    const float* W1 = (const float*)d_in[2];
    const float* b1 = (const float*)d_in[3];
    const float* W2 = (const float*)d_in[4];
    const float* b2 = (const float*)d_in[5];
    float* out = (float*)d_out;

    const int N = in_sizes[0] / IN_F;
    const int E = in_sizes[1] / 2;
    const int* src = ei;        // edge_index[0]
    const int* dst = ei + E;    // edge_index[1]

    char* ws = (char*)d_ws;
    const size_t MB = 1u << 20;
    int*      gcount  = (int*)     (ws + 0 * MB);            // 256 ints
    int*      bbase   = (int*)     (ws + 0 * MB + 4096);     // 257 ints
    int*      gcursor = (int*)     (ws + 0 * MB + 8192);     // 256 ints
    int*      rowptr  = (int*)     (ws + 1 * MB);            // N+1 ints
    float*    dinv    = (float*)   (ws + 2 * MB);            // N floats
    unsigned* gbin    = (unsigned*)(ws + 3 * MB);            // E uints (6.4 MB)
    int*      col     = (int*)     (ws + 10 * MB);           // E ints  (6.4 MB)
    ushort_t* xws     = (ushort_t*)(ws + 20 * MB);           // N*64 bf16 (12.8 MB)
    float*    h       = (float*)   (ws + 40 * MB);           // N*64 floats (25.6 MB)

    const int nbE = (E + CHUNK - 1) / CHUNK;                 // 391
    const int nbB = (N + BKT_SIZE - 1) / BKT_SIZE;           // 196 buckets (<= 256)

    hipMemsetAsync(gcount, 0, 256 * sizeof(int), stream);
    k_bcount<<<nbE, 256, 0, stream>>>(dst, gcount, E);
    k_bscan <<<1, 256, 0, stream>>>(gcount, bbase, gcursor, rowptr, N, E);
    k_bin   <<<nbE, 256, 0, stream>>>(src, dst, gcursor, gbin, E);
    k_fill2 <<<nbB, 256, 0, stream>>>(gbin, bbase, rowptr, dinv, col, N);

    // layer 1: xws = bf16((x @ W1) * dinv) ; h = relu(dinv*(sum + self) + b1)
    k_gemm<IN_F> <<<(N + 63) / 64, 256, 0, stream>>>(x, W1, dinv, xws, N);
    k_aggregate  <<<(N * 64 + 255) / 256, 256, 0, stream>>>(xws, rowptr, col, dinv, b1, h, N, 1);

    // layer 2: xws = bf16((h @ W2) * dinv) ; out = dinv*(sum + self) + b2
    k_gemm<HID_F><<<(N + 63) / 64, 256, 0, stream>>>(h, W2, dinv, xws, N);
    k_aggregate  <<<(N * 64 + 255) / 256, 256, 0, stream>>>(xws, rowptr, col, dinv, b2, out, N, 0);
}

// Round 5
// 254.732 us; speedup vs baseline: 2.3722x; 1.1710x over previous
//
#include <hip/hip_runtime.h>

#define IN_F 128
#define HID_F 64
#define BKT_SHIFT 9            // 512 nodes per bucket
#define BKT_SIZE 512
#define CHUNK 4096             // edges per block in binning kernels

typedef unsigned short ushort_t;
typedef __attribute__((ext_vector_type(8))) short bf16x8;
typedef __attribute__((ext_vector_type(4))) float f32x4;

__device__ inline ushort_t f2bf(float f) {     // RNE fp32 -> bf16 bits
    unsigned u = __float_as_uint(f);
    u += 0x7FFFu + ((u >> 16) & 1u);
    return (ushort_t)(u >> 16);
}
__device__ inline float bf2f(ushort_t u) {
    return __uint_as_float((unsigned)u << 16);
}

// ---------------- CSR build via 2-level bucket sort by dst ----------------
// pack: (dst & 511) << 23 | src   (needs src < 2^23, nodes/bucket <= 512)

__global__ __launch_bounds__(256) void k_bcount(const int* __restrict__ dst,
        int* __restrict__ gcount, int E) {
    __shared__ int hist[256];
    int tid = threadIdx.x;
    hist[tid] = 0;
    __syncthreads();
    int e0 = blockIdx.x * CHUNK, e1 = min(e0 + CHUNK, E);
    for (int e = e0 + tid; e < e1; e += 256)
        atomicAdd(&hist[dst[e] >> BKT_SHIFT], 1);
    __syncthreads();
    if (hist[tid]) atomicAdd(&gcount[tid], hist[tid]);
}

__global__ __launch_bounds__(256) void k_bscan(const int* __restrict__ gcount,
        int* __restrict__ bbase, int* __restrict__ gcursor,
        int* __restrict__ rowptr, int N, int E) {
    __shared__ int s[256];
    int tid = threadIdx.x;
    int c = gcount[tid];
    s[tid] = c;
    __syncthreads();
    for (int off = 1; off < 256; off <<= 1) {
        int v = (tid >= off) ? s[tid - off] : 0;
        __syncthreads();
        s[tid] += v;
        __syncthreads();
    }
    int excl = s[tid] - c;
    bbase[tid] = excl;
    gcursor[tid] = excl;
    if (tid == 255) bbase[256] = s[255];   // == E
    if (tid == 0) rowptr[N] = E;
}

__global__ __launch_bounds__(256) void k_bin(const int* __restrict__ src,
        const int* __restrict__ dst, int* __restrict__ gcursor,
        unsigned* __restrict__ gbin, int E) {
    __shared__ int hist[256];
    __shared__ int cur[256];
    int tid = threadIdx.x;
    hist[tid] = 0;
    __syncthreads();
    int e0 = blockIdx.x * CHUNK, e1 = min(e0 + CHUNK, E);
    for (int e = e0 + tid; e < e1; e += 256)
        atomicAdd(&hist[dst[e] >> BKT_SHIFT], 1);
    __syncthreads();
    if (hist[tid]) cur[tid] = atomicAdd(&gcursor[tid], hist[tid]);
    __syncthreads();
    for (int e = e0 + tid; e < e1; e += 256) {
        int d = dst[e];
        int b = d >> BKT_SHIFT;
        int p = atomicAdd(&cur[b], 1);
        gbin[p] = ((unsigned)(d & (BKT_SIZE - 1)) << 23) | (unsigned)src[e];
    }
}

__global__ __launch_bounds__(256) void k_fill2(const unsigned* __restrict__ gbin,
        const int* __restrict__ bbase, int* __restrict__ rowptr,
        float* __restrict__ dinv, int* __restrict__ col, int N) {
    __shared__ int cnt[BKT_SIZE];
    __shared__ int pos[BKT_SIZE];
    __shared__ int s[256];
    int tid = threadIdx.x;
    int b = blockIdx.x;
    int e0 = bbase[b], e1 = bbase[b + 1];
    cnt[tid] = 0; cnt[tid + 256] = 0;
    __syncthreads();
    for (int e = e0 + tid; e < e1; e += 256)
        atomicAdd(&cnt[gbin[e] >> 23], 1);
    __syncthreads();
    int c0 = cnt[2 * tid], c1 = cnt[2 * tid + 1];
    int p2 = c0 + c1;
    s[tid] = p2;
    __syncthreads();
    for (int off = 1; off < 256; off <<= 1) {
        int v = (tid >= off) ? s[tid - off] : 0;
        __syncthreads();
        s[tid] += v;
        __syncthreads();
    }
    int excl = s[tid] - p2;
    pos[2 * tid] = excl;
    pos[2 * tid + 1] = excl + c0;
    __syncthreads();
    int n0 = b << BKT_SHIFT;
    #pragma unroll
    for (int i = tid; i < BKT_SIZE; i += 256) {
        int n = n0 + i;
        if (n < N) {
            rowptr[n] = e0 + pos[i];
            dinv[n] = rsqrtf((float)cnt[i] + 1.0f);   // +1 self-loop
        }
    }
    __syncthreads();
    for (int e = e0 + tid; e < e1; e += 256) {
        unsigned v = gbin[e];
        int p = atomicAdd(&pos[v >> 23], 1);
        col[e0 + p] = (int)(v & 0x7FFFFFu);
    }
}

// ---------------- W pre-pack into MFMA B-fragment order (bf16) ----------------
// B-frag (16x16x32): lane holds B[k = (lane>>4)*8 + j][n = lane&15], j=0..7.
// Bp[((s*4 + t)*64 + lane)*8 + j] = W[(s*32 + (lane>>4)*8 + j)*64 + t*16 + (lane&15)]
__global__ void k_pack(const float* __restrict__ W1, const float* __restrict__ W2,
                       ushort_t* __restrict__ Bp1, ushort_t* __restrict__ Bp2) {
    int tid = blockIdx.x * 256 + threadIdx.x;
    int id = (tid < 8192) ? tid : tid - 8192;
    int j = id & 7, lane = (id >> 3) & 63, t = (id >> 9) & 3, s = id >> 11;
    int k = s * 32 + ((lane >> 4) << 3) + j;
    int n = t * 16 + (lane & 15);
    if (tid < 8192)        Bp1[id] = f2bf(W1[k * 64 + n]);        // K=128: s in 0..3
    else if (tid < 12288)  Bp2[id] = f2bf(W2[k * 64 + n]);        // K=64 : s in 0..1
}

// ---------------- MFMA GEMM: out[N,64] = bf16((A[N,K] @ W) * dinv[row]) ----------------
// 4 waves/block, wave = 16 rows x 64 cols. A-frag straight from global
// (fp32 converted in-register for layer 1, bf16 direct for layer 2).
template<int K, typename AT>
__global__ __launch_bounds__(256) void k_gemm_mfma(const AT* __restrict__ A,
        const ushort_t* __restrict__ Bp, const float* __restrict__ dinv,
        ushort_t* __restrict__ out, int N) {
    int wave = threadIdx.x >> 6, lane = threadIdx.x & 63;
    int m = lane & 15, q = lane >> 4;
    int row0 = blockIdx.x * 64 + wave * 16;
    int arow = row0 + m;
    int arowc = (arow < N) ? arow : (N - 1);
    f32x4 acc[4] = {};
    #pragma unroll
    for (int s = 0; s < K / 32; ++s) {
        bf16x8 af;
        if constexpr (sizeof(AT) == 4) {
            const float* ap = (const float*)A + (size_t)arowc * K + s * 32 + q * 8;
            float4 x0 = *(const float4*)ap;
            float4 x1 = *(const float4*)(ap + 4);
            af[0] = (short)f2bf(x0.x); af[1] = (short)f2bf(x0.y);
            af[2] = (short)f2bf(x0.z); af[3] = (short)f2bf(x0.w);
            af[4] = (short)f2bf(x1.x); af[5] = (short)f2bf(x1.y);
            af[6] = (short)f2bf(x1.z); af[7] = (short)f2bf(x1.w);
        } else {
            af = *(const bf16x8*)((const ushort_t*)A + (size_t)arowc * K + s * 32 + q * 8);
        }
        #pragma unroll
        for (int t = 0; t < 4; ++t) {
            bf16x8 bf = *(const bf16x8*)(Bp + (size_t)((s * 4 + t) * 64 + lane) * 8);
            acc[t] = __builtin_amdgcn_mfma_f32_16x16x32_bf16(af, bf, acc[t], 0, 0, 0);
        }
    }
    // C/D layout: col = lane&15, row = q*4 + r  [m89-verified]
    int orow0 = row0 + q * 4;
    float4 d4 = *(const float4*)(dinv + orow0);   // ws slack makes OOB read safe
    #pragma unroll
    for (int r = 0; r < 4; ++r) {
        int row = orow0 + r;
        if (row < N) {
            float dn = (r == 0) ? d4.x : (r == 1) ? d4.y : (r == 2) ? d4.z : d4.w;
            #pragma unroll
            for (int t = 0; t < 4; ++t)
                out[(size_t)row * 64 + t * 16 + m] = f2bf(acc[t][r] * dn);
        }
    }
}

// ---------------- pull aggregation: 16 lanes/node, 4 nodes/wave ----------------
// lane i of a group covers features i*4..i*4+3 (ushort4 = 8B loads).
// Each gather instr fetches 4 independent random 128B lines (one per group).
__global__ __launch_bounds__(256) void k_aggregate(const ushort_t* __restrict__ xws,
        const int* __restrict__ rowptr, const int* __restrict__ col,
        const float* __restrict__ dinv, const float* __restrict__ bias,
        float* __restrict__ outf, ushort_t* __restrict__ outb, int N, int relu_bf16) {
    int n = (blockIdx.x * 256 + threadIdx.x) >> 4;
    int i = threadIdx.x & 15;
    if (n >= N) return;
    int beg = rowptr[n], end = rowptr[n + 1];
    float dn = dinv[n];
    const ushort_t* base = xws + i * 4;
    ushort4 sv = *(const ushort4*)(base + (size_t)n * 64);
    float ac[4][4] = {};
    ac[0][0] = bf2f(sv.x); ac[0][1] = bf2f(sv.y);
    ac[0][2] = bf2f(sv.z); ac[0][3] = bf2f(sv.w);
    int e = beg;
    for (; e + 4 <= end; e += 4) {
        int c0 = col[e + 0], c1 = col[e + 1], c2 = col[e + 2], c3 = col[e + 3];
        ushort4 v0 = *(const ushort4*)(base + (size_t)c0 * 64);
        ushort4 v1 = *(const ushort4*)(base + (size_t)c1 * 64);
        ushort4 v2 = *(const ushort4*)(base + (size_t)c2 * 64);
        ushort4 v3 = *(const ushort4*)(base + (size_t)c3 * 64);
        ac[0][0] += bf2f(v0.x); ac[0][1] += bf2f(v0.y); ac[0][2] += bf2f(v0.z); ac[0][3] += bf2f(v0.w);
        ac[1][0] += bf2f(v1.x); ac[1][1] += bf2f(v1.y); ac[1][2] += bf2f(v1.z); ac[1][3] += bf2f(v1.w);
        ac[2][0] += bf2f(v2.x); ac[2][1] += bf2f(v2.y); ac[2][2] += bf2f(v2.z); ac[2][3] += bf2f(v2.w);
        ac[3][0] += bf2f(v3.x); ac[3][1] += bf2f(v3.y); ac[3][2] += bf2f(v3.z); ac[3][3] += bf2f(v3.w);
    }
    for (; e < end; ++e) {
        int c = col[e];
        ushort4 v = *(const ushort4*)(base + (size_t)c * 64);
        ac[0][0] += bf2f(v.x); ac[0][1] += bf2f(v.y);
        ac[0][2] += bf2f(v.z); ac[0][3] += bf2f(v.w);
    }
    float4 b4 = *(const float4*)(bias + i * 4);
    float r0 = dn * (ac[0][0] + ac[1][0] + ac[2][0] + ac[3][0]) + b4.x;
    float r1 = dn * (ac[0][1] + ac[1][1] + ac[2][1] + ac[3][1]) + b4.y;
    float r2 = dn * (ac[0][2] + ac[1][2] + ac[2][2] + ac[3][2]) + b4.z;
    float r3 = dn * (ac[0][3] + ac[1][3] + ac[2][3] + ac[3][3]) + b4.w;
    if (relu_bf16) {
        ushort4 o;
        o.x = f2bf(fmaxf(r0, 0.f)); o.y = f2bf(fmaxf(r1, 0.f));
        o.z = f2bf(fmaxf(r2, 0.f)); o.w = f2bf(fmaxf(r3, 0.f));
        *(ushort4*)(outb + (size_t)n * 64 + i * 4) = o;
    } else {
        float4 o = {r0, r1, r2, r3};
        *(float4*)(outf + (size_t)n * 64 + i * 4) = o;
    }
}

// ---------------- launch ----------------

extern "C" void kernel_launch(void* const* d_in, const int* in_sizes, int n_in,
                              void* d_out, int out_size, void* d_ws, size_t ws_size,
                              hipStream_t stream) {
    const float* x  = (const float*)d_in[0];
    const int*   ei = (const int*)d_in[1];
    const float* W1 = (const float*)d_in[2];
    const float* b1 = (const float*)d_in[3];
    const float* W2 = (const float*)d_in[4];
    const float* b2 = (const float*)d_in[5];
    float* out = (float*)d_out;

    const int N = in_sizes[0] / IN_F;
    const int E = in_sizes[1] / 2;
    const int* src = ei;        // edge_index[0]
    const int* dst = ei + E;    // edge_index[1]

    char* ws = (char*)d_ws;
    const size_t MB = 1u << 20;
    int*      gcount  = (int*)     (ws + 0 * MB);            // 256 ints
    int*      bbase   = (int*)     (ws + 4096);              // 257 ints
    int*      gcursor = (int*)     (ws + 8192);              // 256 ints
    ushort_t* Bp1     = (ushort_t*)(ws + 16384);             // 8192 bf16 (16 KB)
    ushort_t* Bp2     = (ushort_t*)(ws + 49152);             // 4096 bf16 (8 KB)
    int*      rowptr  = (int*)     (ws + 1 * MB);            // N+1 ints
    float*    dinv    = (float*)   (ws + 2 * MB);            // N floats (+slack)
    unsigned* gbin    = (unsigned*)(ws + 3 * MB);            // E uints (6.4 MB)
    int*      col     = (int*)     (ws + 10 * MB);           // E ints  (6.4 MB)
    ushort_t* xws     = (ushort_t*)(ws + 20 * MB);           // N*64 bf16 (12.8 MB)
    ushort_t* h       = (ushort_t*)(ws + 36 * MB);           // N*64 bf16 (12.8 MB)

    const int nbE = (E + CHUNK - 1) / CHUNK;                 // 391
    const int nbB = (N + BKT_SIZE - 1) / BKT_SIZE;           // 196 buckets (<= 256)
    const int nbG = (N + 63) / 64;                           // GEMM blocks
    const int nbA = (N * 16 + 255) / 256;                    // aggregate blocks

    hipMemsetAsync(gcount, 0, 256 * sizeof(int), stream);
    k_pack  <<<48, 256, 0, stream>>>(W1, W2, Bp1, Bp2);
    k_bcount<<<nbE, 256, 0, stream>>>(dst, gcount, E);
    k_bscan <<<1, 256, 0, stream>>>(gcount, bbase, gcursor, rowptr, N, E);
    k_bin   <<<nbE, 256, 0, stream>>>(src, dst, gcursor, gbin, E);
    k_fill2 <<<nbB, 256, 0, stream>>>(gbin, bbase, rowptr, dinv, col, N);

    // layer 1: xws = bf16((x @ W1) * dinv) ; h = bf16(relu(dinv*(sum+self) + b1))
    k_gemm_mfma<IN_F, float>   <<<nbG, 256, 0, stream>>>(x, Bp1, dinv, xws, N);
    k_aggregate<<<nbA, 256, 0, stream>>>(xws, rowptr, col, dinv, b1, nullptr, h, N, 1);

    // layer 2: xws = bf16((h @ W2) * dinv) ; out = dinv*(sum+self) + b2  (fp32)
    k_gemm_mfma<HID_F, ushort_t><<<nbG, 256, 0, stream>>>(h, Bp2, dinv, xws, N);
    k_aggregate<<<nbA, 256, 0, stream>>>(xws, rowptr, col, dinv, b2, out, nullptr, N, 0);
}